// Round 1
// baseline (3290.096 us; speedup 1.0000x reference)
//
#include <hip/hip_runtime.h>

#define D 128
#define NNODES 100000
#define NEDGES 1600000
#define BN_EPS 1e-5f
#define NB_STATS 1024

// Scratch lives inside d_out's E_X region; E_X copy happens LAST and
// overwrites it. Offsets in floats:
//   H     : [0, 12.8M)
//   BX    : [12.8M, 25.6M)
//   agg   : [25.6M, 38.4M)
//   indeg : [38.4M, 38.5M)   (int)
//   psum  : [38.5M, +131072)
//   psq   : [38,631,072, +131072)
//   scale : [38,762,144, +128)
//   shift : [38,762,272, +128)
#define OFF_BX     12800000
#define OFF_AGG    25600000
#define OFF_INDEG  38400000
#define OFF_PSUM   38500000
#define OFF_PSQ    38631072
#define OFF_SCALE  38762144
#define OFF_SHIFT  38762272

// ---------------------------------------------------------------------------
// GEMM: Y[i,d] = sum_k X[i,k] * W[d,k] + bias[d]
// Even blocks -> A (writes agg = AX), odd blocks -> B (writes BX).
// W staged in LDS (stride 132 floats, 16B aligned). Each thread: 4 rows x 4
// cols (cols cg, cg+32, cg+64, cg+96), so 64 FMAs per 8 vector loads.
// ---------------------------------------------------------------------------
__global__ __launch_bounds__(256, 2) void gemm2_kernel(
    const float* __restrict__ X,
    const float* __restrict__ Aw, const float* __restrict__ Ab,
    const float* __restrict__ Bw, const float* __restrict__ Bb,
    float* __restrict__ AX, float* __restrict__ BXo)
{
    const bool isB = (blockIdx.x & 1);
    const float* __restrict__ W    = isB ? Bw : Aw;
    const float* __restrict__ bias = isB ? Bb : Ab;
    float* __restrict__ Y          = isB ? BXo : AX;

    __shared__ float Ws[D * 132];
    const float4* W4 = (const float4*)W;
    for (int i = threadIdx.x; i < D * D / 4; i += 256) {
        int d  = i >> 5;      // W row (= output col), 32 float4 per row
        int k4 = i & 31;
        float4 w = W4[i];
        *(float4*)&Ws[d * 132 + 4 * k4] = w;
    }
    __syncthreads();

    const int rg = threadIdx.x >> 5;   // 0..7  -> 4 rows each
    const int cg = threadIdx.x & 31;   // 0..31 -> cols cg+32j

    float b[4];
#pragma unroll
    for (int j = 0; j < 4; ++j) b[j] = bias[cg + 32 * j];

    const int ntiles = NNODES / 32;    // 3125 exact
    for (int t = (blockIdx.x >> 1); t < ntiles; t += (gridDim.x >> 1)) {
        const int row0 = t * 32 + rg * 4;
        float acc[4][4];
#pragma unroll
        for (int r = 0; r < 4; ++r)
#pragma unroll
            for (int j = 0; j < 4; ++j) acc[r][j] = b[j];

        const float* xbase = X + (size_t)row0 * D;
#pragma unroll 4
        for (int k = 0; k < D; k += 4) {
            float4 xr[4];
#pragma unroll
            for (int r = 0; r < 4; ++r)
                xr[r] = *(const float4*)&xbase[r * D + k];
            float4 wv[4];
#pragma unroll
            for (int j = 0; j < 4; ++j)
                wv[j] = *(const float4*)&Ws[(cg + 32 * j) * 132 + k];
#pragma unroll
            for (int r = 0; r < 4; ++r)
#pragma unroll
                for (int j = 0; j < 4; ++j)
                    acc[r][j] += xr[r].x * wv[j].x + xr[r].y * wv[j].y +
                                 xr[r].z * wv[j].z + xr[r].w * wv[j].w;
        }
#pragma unroll
        for (int r = 0; r < 4; ++r) {
            float* yrow = Y + (size_t)(row0 + r) * D;
#pragma unroll
            for (int j = 0; j < 4; ++j) yrow[cg + 32 * j] = acc[r][j];
        }
    }
}

// ---------------------------------------------------------------------------
// Edge scatter: agg[dst] += BX[src], indeg[dst] += 1.
// 32 lanes per edge, float4 per lane; 8 edges per 256-thread block iter.
// ---------------------------------------------------------------------------
__global__ __launch_bounds__(256) void scatter_kernel(
    const float* __restrict__ BX, const int* __restrict__ src,
    const int* __restrict__ dst, float* __restrict__ agg,
    int* __restrict__ indeg)
{
    const int group = threadIdx.x >> 5;
    const int lane  = threadIdx.x & 31;
    for (int e = blockIdx.x * 8 + group; e < NEDGES; e += gridDim.x * 8) {
        const int s = src[e];
        const int t = dst[e];
        float4 v = *(const float4*)&BX[s * D + lane * 4];
        float* ap = &agg[t * D + lane * 4];
        atomicAdd(ap + 0, v.x);
        atomicAdd(ap + 1, v.y);
        atomicAdd(ap + 2, v.z);
        atomicAdd(ap + 3, v.w);
        if (lane == 0) atomicAdd(&indeg[t], 1);
    }
}

// ---------------------------------------------------------------------------
// Hpre = (indeg>0 ? agg : X) * snorm_n ; write to d_out H region and
// accumulate per-block column sum / sumsq partials.
// ---------------------------------------------------------------------------
__global__ __launch_bounds__(256) void hpre_kernel(
    const float* __restrict__ agg, const int* __restrict__ indeg,
    const float* __restrict__ X, const float* __restrict__ snorm,
    float* __restrict__ Hpre, float* __restrict__ psum,
    float* __restrict__ psq)
{
    const int d   = threadIdx.x & 127;
    const int sub = threadIdx.x >> 7;   // 0..1
    float s = 0.f, q = 0.f;
    for (int i = blockIdx.x * 2 + sub; i < NNODES; i += gridDim.x * 2) {
        float h;
        if (indeg[i] > 0) h = agg[(size_t)i * D + d];
        else              h = X[(size_t)i * D + d];
        h *= snorm[i];
        Hpre[(size_t)i * D + d] = h;
        s += h;
        q += h * h;
    }
    __shared__ float ls[256], lq[256];
    ls[threadIdx.x] = s;
    lq[threadIdx.x] = q;
    __syncthreads();
    if (threadIdx.x < 128) {
        psum[blockIdx.x * D + d] = ls[d] + ls[d + 128];
        psq [blockIdx.x * D + d] = lq[d] + lq[d + 128];
    }
}

// ---------------------------------------------------------------------------
// Reduce partials -> scale/shift for fused BN.
// ---------------------------------------------------------------------------
__global__ void bnstats_kernel(
    const float* __restrict__ psum, const float* __restrict__ psq,
    const float* __restrict__ gamma, const float* __restrict__ beta,
    float* __restrict__ scale, float* __restrict__ shift)
{
    const int d = threadIdx.x;
    float s = 0.f, q = 0.f;
    for (int b = 0; b < NB_STATS; ++b) {
        s += psum[b * D + d];
        q += psq [b * D + d];
    }
    const float inv_n = 1.0f / (float)NNODES;
    float mean = s * inv_n;
    float var  = q * inv_n - mean * mean;
    float sc   = rsqrtf(var + BN_EPS) * gamma[d];
    scale[d] = sc;
    shift[d] = beta[d] - mean * sc;
}

// ---------------------------------------------------------------------------
// out = X + relu(Hpre * scale + shift), in place over the H region.
// ---------------------------------------------------------------------------
__global__ __launch_bounds__(256) void final_kernel(
    const float* __restrict__ Hpre, const float* __restrict__ X,
    const float* __restrict__ scale, const float* __restrict__ shift,
    float* __restrict__ out)
{
    const int total = NNODES * D / 4;
    for (int i = blockIdx.x * 256 + threadIdx.x; i < total;
         i += gridDim.x * 256) {
        float4 h = ((const float4*)Hpre)[i];
        float4 x = ((const float4*)X)[i];
        int d0 = (i * 4) & 127;
        float4 r;
        r.x = x.x + fmaxf(0.f, h.x * scale[d0 + 0] + shift[d0 + 0]);
        r.y = x.y + fmaxf(0.f, h.y * scale[d0 + 1] + shift[d0 + 1]);
        r.z = x.z + fmaxf(0.f, h.z * scale[d0 + 2] + shift[d0 + 2]);
        r.w = x.w + fmaxf(0.f, h.w * scale[d0 + 3] + shift[d0 + 3]);
        ((float4*)out)[i] = r;
    }
}

extern "C" void kernel_launch(void* const* d_in, const int* in_sizes, int n_in,
                              void* d_out, int out_size, void* d_ws, size_t ws_size,
                              hipStream_t stream)
{
    const float* X       = (const float*)d_in[0];
    const float* E_X     = (const float*)d_in[1];
    const float* snorm_n = (const float*)d_in[2];
    // d_in[3] = snorm_e (unused by the reference output)
    const int*   src     = (const int*)d_in[4];
    const int*   dst     = (const int*)d_in[5];
    const float* A_w     = (const float*)d_in[6];
    const float* A_b     = (const float*)d_in[7];
    const float* B_w     = (const float*)d_in[8];
    const float* B_b     = (const float*)d_in[9];
    const float* gamma   = (const float*)d_in[10];
    const float* beta    = (const float*)d_in[11];

    float* out = (float*)d_out;

    float* BX    = out + OFF_BX;
    float* agg   = out + OFF_AGG;
    int*   indeg = (int*)(out + OFF_INDEG);
    float* psum  = out + OFF_PSUM;
    float* psq   = out + OFF_PSQ;
    float* scale = out + OFF_SCALE;
    float* shift = out + OFF_SHIFT;

    hipMemsetAsync(indeg, 0, NNODES * sizeof(int), stream);

    gemm2_kernel<<<512, 256, 0, stream>>>(X, A_w, A_b, B_w, B_b, agg, BX);
    scatter_kernel<<<8192, 256, 0, stream>>>(BX, src, dst, agg, indeg);
    hpre_kernel<<<NB_STATS, 256, 0, stream>>>(agg, indeg, X, snorm_n,
                                              out, psum, psq);
    bnstats_kernel<<<1, D, 0, stream>>>(psum, psq, gamma, beta, scale, shift);
    final_kernel<<<2048, 256, 0, stream>>>(out, X, scale, shift, out);

    // E_X passthrough LAST: overwrites the scratch region.
    hipMemcpyAsync(out + (size_t)NNODES * D, E_X,
                   (size_t)NEDGES * D * sizeof(float),
                   hipMemcpyDeviceToDevice, stream);
}

// Round 2
// 1133.522 us; speedup vs baseline: 2.9025x; 2.9025x over previous
//
#include <hip/hip_runtime.h>

#define D 128
#define NNODES 100000
#define NEDGES 1600000
#define BN_EPS 1e-5f
#define NB_STATS 2048

// Scratch lives inside d_out's E_X region; E_X copy happens LAST and
// overwrites it. Offsets in float slots from `out`:
#define OFF_BX     12800000   // [12.8M, 25.6M)   BX
#define OFF_AX     25600000   // [25.6M, 38.4M)   AX
#define OFF_ESRC   38400000   // 1.6M ints        edge srcs sorted by dst
#define OFF_INDEG  40000000   // 100k ints
#define OFF_ROWS   40100000   // 100001 ints      CSR row starts
#define OFF_CURS   40250000   // 100k ints        fill cursors
#define OFF_PSUM   40400000   // 2048*128 floats
#define OFF_PSQ    40700000   // 2048*128 floats
#define OFF_SCALE  41000000   // 128
#define OFF_SHIFT  41000128   // 128

// ---------------------------------------------------------------------------
// GEMM: Y[i,d] = sum_k X[i,k] * W[d,k] + bias[d]
// Even blocks -> A (writes AX), odd blocks -> B (writes BX).
// ---------------------------------------------------------------------------
__global__ __launch_bounds__(256, 2) void gemm2_kernel(
    const float* __restrict__ X,
    const float* __restrict__ Aw, const float* __restrict__ Ab,
    const float* __restrict__ Bw, const float* __restrict__ Bb,
    float* __restrict__ AX, float* __restrict__ BXo)
{
    const bool isB = (blockIdx.x & 1);
    const float* __restrict__ W    = isB ? Bw : Aw;
    const float* __restrict__ bias = isB ? Bb : Ab;
    float* __restrict__ Y          = isB ? BXo : AX;

    __shared__ float Ws[D * 132];
    const float4* W4 = (const float4*)W;
    for (int i = threadIdx.x; i < D * D / 4; i += 256) {
        int d  = i >> 5;
        int k4 = i & 31;
        float4 w = W4[i];
        *(float4*)&Ws[d * 132 + 4 * k4] = w;
    }
    __syncthreads();

    const int rg = threadIdx.x >> 5;   // 0..7  -> 4 rows each
    const int cg = threadIdx.x & 31;   // 0..31 -> cols cg+32j

    float b[4];
#pragma unroll
    for (int j = 0; j < 4; ++j) b[j] = bias[cg + 32 * j];

    const int ntiles = NNODES / 32;    // 3125 exact
    for (int t = (blockIdx.x >> 1); t < ntiles; t += (gridDim.x >> 1)) {
        const int row0 = t * 32 + rg * 4;
        float acc[4][4];
#pragma unroll
        for (int r = 0; r < 4; ++r)
#pragma unroll
            for (int j = 0; j < 4; ++j) acc[r][j] = b[j];

        const float* xbase = X + (size_t)row0 * D;
#pragma unroll 4
        for (int k = 0; k < D; k += 4) {
            float4 xr[4];
#pragma unroll
            for (int r = 0; r < 4; ++r)
                xr[r] = *(const float4*)&xbase[r * D + k];
            float4 wv[4];
#pragma unroll
            for (int j = 0; j < 4; ++j)
                wv[j] = *(const float4*)&Ws[(cg + 32 * j) * 132 + k];
#pragma unroll
            for (int r = 0; r < 4; ++r)
#pragma unroll
                for (int j = 0; j < 4; ++j)
                    acc[r][j] += xr[r].x * wv[j].x + xr[r].y * wv[j].y +
                                 xr[r].z * wv[j].z + xr[r].w * wv[j].w;
        }
#pragma unroll
        for (int r = 0; r < 4; ++r) {
            float* yrow = Y + (size_t)(row0 + r) * D;
#pragma unroll
            for (int j = 0; j < 4; ++j) yrow[cg + 32 * j] = acc[r][j];
        }
    }
}

// ---------------------------------------------------------------------------
// Histogram of in-degrees (int atomics only).
// ---------------------------------------------------------------------------
__global__ __launch_bounds__(256) void hist_kernel(
    const int* __restrict__ dst, int* __restrict__ indeg)
{
    for (int e = blockIdx.x * 256 + threadIdx.x; e < NEDGES;
         e += gridDim.x * 256)
        atomicAdd(&indeg[dst[e]], 1);
}

// ---------------------------------------------------------------------------
// Single-block exclusive scan of indeg -> row_start[0..N], cursor copy.
// ---------------------------------------------------------------------------
#define SCAN_T 1024
#define SCAN_CHUNK 98   // ceil(100000/1024)
__global__ __launch_bounds__(SCAN_T) void scan_kernel(
    const int* __restrict__ indeg, int* __restrict__ rows,
    int* __restrict__ curs)
{
    __shared__ int ls[SCAN_T];
    const int t = threadIdx.x;
    const int begin = t * SCAN_CHUNK;
    const int end   = min(begin + SCAN_CHUNK, NNODES);
    int s = 0;
    for (int i = begin; i < end; ++i) s += indeg[i];
    ls[t] = s;
    __syncthreads();
    for (int off = 1; off < SCAN_T; off <<= 1) {
        int v = (t >= off) ? ls[t - off] : 0;
        __syncthreads();
        ls[t] += v;
        __syncthreads();
    }
    int prefix = (t == 0) ? 0 : ls[t - 1];
    for (int i = begin; i < end; ++i) {
        rows[i] = prefix;
        curs[i] = prefix;
        prefix += indeg[i];
    }
    if (t == SCAN_T - 1) rows[NNODES] = ls[SCAN_T - 1];
}

// ---------------------------------------------------------------------------
// Fill CSR: esrc[pos] = src[e], pos via per-node cursor (int atomics).
// ---------------------------------------------------------------------------
__global__ __launch_bounds__(256) void fill_kernel(
    const int* __restrict__ src, const int* __restrict__ dst,
    int* __restrict__ curs, int* __restrict__ esrc)
{
    for (int e = blockIdx.x * 256 + threadIdx.x; e < NEDGES;
         e += gridDim.x * 256) {
        int pos = atomicAdd(&curs[dst[e]], 1);
        esrc[pos] = src[e];
    }
}

// ---------------------------------------------------------------------------
// Gather-aggregate + fused Hpre: one wave per node, 64 lanes x float2.
// h = (deg>0 ? AX[i] + sum_e BX[esrc[e]] : X[i]) * snorm[i]
// Writes Hpre, accumulates per-block BN partials.
// ---------------------------------------------------------------------------
__global__ __launch_bounds__(256, 4) void agg_kernel(
    const float* __restrict__ AX, const float* __restrict__ BX,
    const float* __restrict__ X, const float* __restrict__ snorm,
    const int* __restrict__ rows, const int* __restrict__ esrc,
    float* __restrict__ Hpre, float* __restrict__ psum,
    float* __restrict__ psq)
{
    const int w    = threadIdx.x >> 6;   // wave in block, 0..3
    const int lane = threadIdx.x & 63;
    const int c0   = lane * 2;
    float ps0 = 0.f, ps1 = 0.f, q0 = 0.f, q1 = 0.f;

    for (int i = blockIdx.x * 4 + w; i < NNODES; i += gridDim.x * 4) {
        const int rs = rows[i];
        const int re = rows[i + 1];
        float2 acc;
        if (re > rs) {
            acc = *(const float2*)&AX[(size_t)i * D + c0];
            for (int e = rs; e < re; ++e) {
                const int s = esrc[e];
                float2 v = *(const float2*)&BX[(size_t)s * D + c0];
                acc.x += v.x;
                acc.y += v.y;
            }
        } else {
            acc = *(const float2*)&X[(size_t)i * D + c0];
        }
        const float sn = snorm[i];
        acc.x *= sn;
        acc.y *= sn;
        *(float2*)&Hpre[(size_t)i * D + c0] = acc;
        ps0 += acc.x; ps1 += acc.y;
        q0  += acc.x * acc.x; q1 += acc.y * acc.y;
    }

    __shared__ float sp[4][D], sq[4][D];
    sp[w][c0] = ps0; sp[w][c0 + 1] = ps1;
    sq[w][c0] = q0;  sq[w][c0 + 1] = q1;
    __syncthreads();
    if (threadIdx.x < D) {
        const int c = threadIdx.x;
        psum[blockIdx.x * D + c] = sp[0][c] + sp[1][c] + sp[2][c] + sp[3][c];
        psq [blockIdx.x * D + c] = sq[0][c] + sq[1][c] + sq[2][c] + sq[3][c];
    }
}

// ---------------------------------------------------------------------------
// Reduce partials -> scale/shift for fused BN.
// ---------------------------------------------------------------------------
__global__ __launch_bounds__(1024) void bnstats_kernel(
    const float* __restrict__ psum, const float* __restrict__ psq,
    const float* __restrict__ gamma, const float* __restrict__ beta,
    float* __restrict__ scale, float* __restrict__ shift)
{
    const int c = threadIdx.x & 127;
    const int g = threadIdx.x >> 7;   // 0..7
    float s = 0.f, q = 0.f;
    for (int b = g; b < NB_STATS; b += 8) {
        s += psum[b * D + c];
        q += psq [b * D + c];
    }
    __shared__ float ls[8][D], lq[8][D];
    ls[g][c] = s;
    lq[g][c] = q;
    __syncthreads();
    if (threadIdx.x < D) {
        float S = 0.f, Q = 0.f;
#pragma unroll
        for (int g2 = 0; g2 < 8; ++g2) { S += ls[g2][c]; Q += lq[g2][c]; }
        const float inv_n = 1.0f / (float)NNODES;
        float mean = S * inv_n;
        float var  = Q * inv_n - mean * mean;
        float sc   = rsqrtf(var + BN_EPS) * gamma[c];
        scale[c] = sc;
        shift[c] = beta[c] - mean * sc;
    }
}

// ---------------------------------------------------------------------------
// out = X + relu(Hpre * scale + shift), in place over the H region.
// ---------------------------------------------------------------------------
__global__ __launch_bounds__(256) void final_kernel(
    const float* __restrict__ Hpre, const float* __restrict__ X,
    const float* __restrict__ scale, const float* __restrict__ shift,
    float* __restrict__ out)
{
    const int total = NNODES * D / 4;
    for (int i = blockIdx.x * 256 + threadIdx.x; i < total;
         i += gridDim.x * 256) {
        float4 h = ((const float4*)Hpre)[i];
        float4 x = ((const float4*)X)[i];
        int d0 = (i * 4) & 127;
        float4 r;
        r.x = x.x + fmaxf(0.f, h.x * scale[d0 + 0] + shift[d0 + 0]);
        r.y = x.y + fmaxf(0.f, h.y * scale[d0 + 1] + shift[d0 + 1]);
        r.z = x.z + fmaxf(0.f, h.z * scale[d0 + 2] + shift[d0 + 2]);
        r.w = x.w + fmaxf(0.f, h.w * scale[d0 + 3] + shift[d0 + 3]);
        ((float4*)out)[i] = r;
    }
}

extern "C" void kernel_launch(void* const* d_in, const int* in_sizes, int n_in,
                              void* d_out, int out_size, void* d_ws, size_t ws_size,
                              hipStream_t stream)
{
    const float* X       = (const float*)d_in[0];
    const float* E_X     = (const float*)d_in[1];
    const float* snorm_n = (const float*)d_in[2];
    const int*   src     = (const int*)d_in[4];
    const int*   dst     = (const int*)d_in[5];
    const float* A_w     = (const float*)d_in[6];
    const float* A_b     = (const float*)d_in[7];
    const float* B_w     = (const float*)d_in[8];
    const float* B_b     = (const float*)d_in[9];
    const float* gamma   = (const float*)d_in[10];
    const float* beta    = (const float*)d_in[11];

    float* out = (float*)d_out;

    float* BX    = out + OFF_BX;
    float* AX    = out + OFF_AX;
    int*   esrc  = (int*)(out + OFF_ESRC);
    int*   indeg = (int*)(out + OFF_INDEG);
    int*   rows  = (int*)(out + OFF_ROWS);
    int*   curs  = (int*)(out + OFF_CURS);
    float* psum  = out + OFF_PSUM;
    float* psq   = out + OFF_PSQ;
    float* scale = out + OFF_SCALE;
    float* shift = out + OFF_SHIFT;

    hipMemsetAsync(indeg, 0, NNODES * sizeof(int), stream);

    gemm2_kernel<<<512, 256, 0, stream>>>(X, A_w, A_b, B_w, B_b, AX, BX);
    hist_kernel<<<2048, 256, 0, stream>>>(dst, indeg);
    scan_kernel<<<1, SCAN_T, 0, stream>>>(indeg, rows, curs);
    fill_kernel<<<2048, 256, 0, stream>>>(src, dst, curs, esrc);
    agg_kernel<<<NB_STATS, 256, 0, stream>>>(AX, BX, X, snorm_n, rows, esrc,
                                             out, psum, psq);
    bnstats_kernel<<<1, 1024, 0, stream>>>(psum, psq, gamma, beta, scale, shift);
    final_kernel<<<2048, 256, 0, stream>>>(out, X, scale, shift, out);

    // E_X passthrough LAST: overwrites the scratch region.
    hipMemcpyAsync(out + (size_t)NNODES * D, E_X,
                   (size_t)NEDGES * D * sizeof(float),
                   hipMemcpyDeviceToDevice, stream);
}

// Round 3
// 744.818 us; speedup vs baseline: 4.4173x; 1.5219x over previous
//
#include <hip/hip_runtime.h>

#define D 128
#define NNODES 100000
#define NEDGES 1600000
#define BN_EPS 1e-5f
#define NB_STATS 2048
#define NBLK_P 391   // ceil(NNODES/256)

// Scratch lives inside d_out's E_X region ([12.8M, 217.6M) float slots);
// E_X copy happens LAST and overwrites it. Offsets in float slots:
#define OFF_AX     12800000   // 12.8M f32
#define OFF_BX16   25600000   // 12.8M bf16 (6.4M float slots)
#define OFF_ESRC   32000000   // 1.6M int
#define OFF_ORDER  33600000   // 1.6M int
#define OFF_INDEG  35200000   // 100k int
#define OFF_ROWS   35300000   // 100001 int
#define OFF_LEXC   35500000   // 100k int
#define OFF_BPART  35700000   // 512 int
#define OFF_BSCAN  35701000   // 512 int
#define OFF_PSUM   35800000   // 2048*128 f32
#define OFF_PSQ    36100000   // 2048*128 f32
#define OFF_SCALE  36400000   // 128
#define OFF_SHIFT  36400128   // 128

static __device__ __forceinline__ unsigned short f2bf(float f) {
    unsigned int u = __float_as_uint(f);
    u = (u + 0x7FFF + ((u >> 16) & 1)) >> 16;   // RNE, finite data
    return (unsigned short)u;
}
static __device__ __forceinline__ float bf_lo(unsigned v) {
    return __uint_as_float(v << 16);
}
static __device__ __forceinline__ float bf_hi(unsigned v) {
    return __uint_as_float(v & 0xFFFF0000u);
}

// ---------------------------------------------------------------------------
// GEMM: Y[i,d] = sum_k X[i,k] * W[d,k] + bias[d]
// Even blocks -> A (f32 AX), odd blocks -> B (bf16 BX16).
// ---------------------------------------------------------------------------
__global__ __launch_bounds__(256, 2) void gemm2_kernel(
    const float* __restrict__ X,
    const float* __restrict__ Aw, const float* __restrict__ Ab,
    const float* __restrict__ Bw, const float* __restrict__ Bb,
    float* __restrict__ AX, unsigned short* __restrict__ BX16)
{
    const bool isB = (blockIdx.x & 1);
    const float* __restrict__ W    = isB ? Bw : Aw;
    const float* __restrict__ bias = isB ? Bb : Ab;

    __shared__ float Ws[D * 132];
    const float4* W4 = (const float4*)W;
    for (int i = threadIdx.x; i < D * D / 4; i += 256) {
        int d  = i >> 5;
        int k4 = i & 31;
        float4 w = W4[i];
        *(float4*)&Ws[d * 132 + 4 * k4] = w;
    }
    __syncthreads();

    const int rg = threadIdx.x >> 5;   // 0..7  -> 4 rows each
    const int cg = threadIdx.x & 31;   // 0..31 -> cols cg+32j

    float b[4];
#pragma unroll
    for (int j = 0; j < 4; ++j) b[j] = bias[cg + 32 * j];

    const int ntiles = NNODES / 32;    // 3125 exact
    for (int t = (blockIdx.x >> 1); t < ntiles; t += (gridDim.x >> 1)) {
        const int row0 = t * 32 + rg * 4;
        float acc[4][4];
#pragma unroll
        for (int r = 0; r < 4; ++r)
#pragma unroll
            for (int j = 0; j < 4; ++j) acc[r][j] = b[j];

        const float* xbase = X + (size_t)row0 * D;
#pragma unroll 4
        for (int k = 0; k < D; k += 4) {
            float4 xr[4];
#pragma unroll
            for (int r = 0; r < 4; ++r)
                xr[r] = *(const float4*)&xbase[r * D + k];
            float4 wv[4];
#pragma unroll
            for (int j = 0; j < 4; ++j)
                wv[j] = *(const float4*)&Ws[(cg + 32 * j) * 132 + k];
#pragma unroll
            for (int r = 0; r < 4; ++r)
#pragma unroll
                for (int j = 0; j < 4; ++j)
                    acc[r][j] += xr[r].x * wv[j].x + xr[r].y * wv[j].y +
                                 xr[r].z * wv[j].z + xr[r].w * wv[j].w;
        }
        if (isB) {
#pragma unroll
            for (int r = 0; r < 4; ++r) {
                unsigned short* yrow = BX16 + (size_t)(row0 + r) * D;
#pragma unroll
                for (int j = 0; j < 4; ++j)
                    yrow[cg + 32 * j] = f2bf(acc[r][j]);
            }
        } else {
#pragma unroll
            for (int r = 0; r < 4; ++r) {
                float* yrow = AX + (size_t)(row0 + r) * D;
#pragma unroll
                for (int j = 0; j < 4; ++j) yrow[cg + 32 * j] = acc[r][j];
            }
        }
    }
}

// ---------------------------------------------------------------------------
// Histogram + per-edge rank: order[e] = indeg[dst[e]]++ (int atomics).
// ---------------------------------------------------------------------------
__global__ __launch_bounds__(256) void hist_kernel(
    const int* __restrict__ dst, int* __restrict__ indeg,
    int* __restrict__ order)
{
    for (int e = blockIdx.x * 256 + threadIdx.x; e < NEDGES;
         e += gridDim.x * 256)
        order[e] = atomicAdd(&indeg[dst[e]], 1);
}

// ---------------------------------------------------------------------------
// Parallel scan: (1) per-block local exclusive scan + block totals,
// (2) scan of block totals, (3) add block prefix -> rows.
// ---------------------------------------------------------------------------
__global__ __launch_bounds__(256) void scan1_kernel(
    const int* __restrict__ indeg, int* __restrict__ lexc,
    int* __restrict__ bpart)
{
    __shared__ int ls[256];
    const int i = blockIdx.x * 256 + threadIdx.x;
    const int v = (i < NNODES) ? indeg[i] : 0;
    ls[threadIdx.x] = v;
    __syncthreads();
    for (int off = 1; off < 256; off <<= 1) {
        int u = (threadIdx.x >= off) ? ls[threadIdx.x - off] : 0;
        __syncthreads();
        ls[threadIdx.x] += u;
        __syncthreads();
    }
    if (i < NNODES) lexc[i] = ls[threadIdx.x] - v;
    if (threadIdx.x == 255) bpart[blockIdx.x] = ls[255];
}

__global__ __launch_bounds__(512) void scan2_kernel(
    const int* __restrict__ bpart, int* __restrict__ bscan,
    int* __restrict__ rows)
{
    __shared__ int ls[512];
    const int t = threadIdx.x;
    const int v = (t < NBLK_P) ? bpart[t] : 0;
    ls[t] = v;
    __syncthreads();
    for (int off = 1; off < 512; off <<= 1) {
        int u = (t >= off) ? ls[t - off] : 0;
        __syncthreads();
        ls[t] += u;
        __syncthreads();
    }
    if (t < NBLK_P) bscan[t] = ls[t] - v;    // exclusive
    if (t == 0) rows[NNODES] = NEDGES;
}

__global__ __launch_bounds__(256) void scan3_kernel(
    const int* __restrict__ lexc, const int* __restrict__ bscan,
    int* __restrict__ rows)
{
    const int i = blockIdx.x * 256 + threadIdx.x;
    if (i < NNODES) rows[i] = bscan[blockIdx.x] + lexc[i];
}

// ---------------------------------------------------------------------------
// Fill CSR without atomics: esrc[rows[dst[e]] + order[e]] = src[e].
// ---------------------------------------------------------------------------
__global__ __launch_bounds__(256) void fill_kernel(
    const int* __restrict__ src, const int* __restrict__ dst,
    const int* __restrict__ rows, const int* __restrict__ order,
    int* __restrict__ esrc)
{
    for (int e = blockIdx.x * 256 + threadIdx.x; e < NEDGES;
         e += gridDim.x * 256) {
        esrc[rows[dst[e]] + order[e]] = src[e];
    }
}

// ---------------------------------------------------------------------------
// Gather-aggregate + fused Hpre: one wave per node, 64 lanes x 2 cols.
// BX is bf16 (one u32 per lane = 2 cols). Edge loop unrolled x4 for MLP.
// ---------------------------------------------------------------------------
__global__ __launch_bounds__(256, 4) void agg_kernel(
    const float* __restrict__ AX, const unsigned* __restrict__ BX32,
    const float* __restrict__ X, const float* __restrict__ snorm,
    const int* __restrict__ rows, const int* __restrict__ esrc,
    float* __restrict__ Hpre, float* __restrict__ psum,
    float* __restrict__ psq)
{
    const int w    = threadIdx.x >> 6;   // wave in block, 0..3
    const int lane = threadIdx.x & 63;
    const int c0   = lane * 2;
    float ps0 = 0.f, ps1 = 0.f, q0 = 0.f, q1 = 0.f;

    for (int i = blockIdx.x * 4 + w; i < NNODES; i += gridDim.x * 4) {
        const int rs = rows[i];
        const int re = rows[i + 1];
        float ax, ay;
        if (re > rs) {
            float2 a0 = *(const float2*)&AX[(size_t)i * D + c0];
            ax = a0.x; ay = a0.y;
            int e = rs;
            for (; e + 4 <= re; e += 4) {
                const int s0 = esrc[e + 0], s1 = esrc[e + 1];
                const int s2 = esrc[e + 2], s3 = esrc[e + 3];
                const unsigned v0 = BX32[s0 * 64 + lane];
                const unsigned v1 = BX32[s1 * 64 + lane];
                const unsigned v2 = BX32[s2 * 64 + lane];
                const unsigned v3 = BX32[s3 * 64 + lane];
                ax += bf_lo(v0) + bf_lo(v1) + bf_lo(v2) + bf_lo(v3);
                ay += bf_hi(v0) + bf_hi(v1) + bf_hi(v2) + bf_hi(v3);
            }
            for (; e < re; ++e) {
                const unsigned v = BX32[esrc[e] * 64 + lane];
                ax += bf_lo(v);
                ay += bf_hi(v);
            }
        } else {
            float2 x0 = *(const float2*)&X[(size_t)i * D + c0];
            ax = x0.x; ay = x0.y;
        }
        const float sn = snorm[i];
        ax *= sn; ay *= sn;
        *(float2*)&Hpre[(size_t)i * D + c0] = make_float2(ax, ay);
        ps0 += ax; ps1 += ay;
        q0  += ax * ax; q1 += ay * ay;
    }

    __shared__ float sp[4][D], sq[4][D];
    sp[w][c0] = ps0; sp[w][c0 + 1] = ps1;
    sq[w][c0] = q0;  sq[w][c0 + 1] = q1;
    __syncthreads();
    if (threadIdx.x < D) {
        const int c = threadIdx.x;
        psum[blockIdx.x * D + c] = sp[0][c] + sp[1][c] + sp[2][c] + sp[3][c];
        psq [blockIdx.x * D + c] = sq[0][c] + sq[1][c] + sq[2][c] + sq[3][c];
    }
}

// ---------------------------------------------------------------------------
// Reduce partials -> scale/shift for fused BN.
// ---------------------------------------------------------------------------
__global__ __launch_bounds__(1024) void bnstats_kernel(
    const float* __restrict__ psum, const float* __restrict__ psq,
    const float* __restrict__ gamma, const float* __restrict__ beta,
    float* __restrict__ scale, float* __restrict__ shift)
{
    const int c = threadIdx.x & 127;
    const int g = threadIdx.x >> 7;   // 0..7
    float s = 0.f, q = 0.f;
    for (int b = g; b < NB_STATS; b += 8) {
        s += psum[b * D + c];
        q += psq [b * D + c];
    }
    __shared__ float ls[8][D], lq[8][D];
    ls[g][c] = s;
    lq[g][c] = q;
    __syncthreads();
    if (threadIdx.x < D) {
        float S = 0.f, Q = 0.f;
#pragma unroll
        for (int g2 = 0; g2 < 8; ++g2) { S += ls[g2][c]; Q += lq[g2][c]; }
        const float inv_n = 1.0f / (float)NNODES;
        float mean = S * inv_n;
        float var  = Q * inv_n - mean * mean;
        float sc   = rsqrtf(var + BN_EPS) * gamma[c];
        scale[c] = sc;
        shift[c] = beta[c] - mean * sc;
    }
}

// ---------------------------------------------------------------------------
// out = X + relu(Hpre * scale + shift), in place over the H region.
// ---------------------------------------------------------------------------
__global__ __launch_bounds__(256) void final_kernel(
    const float* __restrict__ Hpre, const float* __restrict__ X,
    const float* __restrict__ scale, const float* __restrict__ shift,
    float* __restrict__ out)
{
    const int total = NNODES * D / 4;
    for (int i = blockIdx.x * 256 + threadIdx.x; i < total;
         i += gridDim.x * 256) {
        float4 h = ((const float4*)Hpre)[i];
        float4 x = ((const float4*)X)[i];
        int d0 = (i * 4) & 127;
        float4 r;
        r.x = x.x + fmaxf(0.f, h.x * scale[d0 + 0] + shift[d0 + 0]);
        r.y = x.y + fmaxf(0.f, h.y * scale[d0 + 1] + shift[d0 + 1]);
        r.z = x.z + fmaxf(0.f, h.z * scale[d0 + 2] + shift[d0 + 2]);
        r.w = x.w + fmaxf(0.f, h.w * scale[d0 + 3] + shift[d0 + 3]);
        ((float4*)out)[i] = r;
    }
}

extern "C" void kernel_launch(void* const* d_in, const int* in_sizes, int n_in,
                              void* d_out, int out_size, void* d_ws, size_t ws_size,
                              hipStream_t stream)
{
    const float* X       = (const float*)d_in[0];
    const float* E_X     = (const float*)d_in[1];
    const float* snorm_n = (const float*)d_in[2];
    const int*   src     = (const int*)d_in[4];
    const int*   dst     = (const int*)d_in[5];
    const float* A_w     = (const float*)d_in[6];
    const float* A_b     = (const float*)d_in[7];
    const float* B_w     = (const float*)d_in[8];
    const float* B_b     = (const float*)d_in[9];
    const float* gamma   = (const float*)d_in[10];
    const float* beta    = (const float*)d_in[11];

    float* out = (float*)d_out;

    float*          AX    = out + OFF_AX;
    unsigned short* BX16  = (unsigned short*)(out + OFF_BX16);
    int*            esrc  = (int*)(out + OFF_ESRC);
    int*            order = (int*)(out + OFF_ORDER);
    int*            indeg = (int*)(out + OFF_INDEG);
    int*            rows  = (int*)(out + OFF_ROWS);
    int*            lexc  = (int*)(out + OFF_LEXC);
    int*            bpart = (int*)(out + OFF_BPART);
    int*            bscan = (int*)(out + OFF_BSCAN);
    float*          psum  = out + OFF_PSUM;
    float*          psq   = out + OFF_PSQ;
    float*          scale = out + OFF_SCALE;
    float*          shift = out + OFF_SHIFT;

    hipMemsetAsync(indeg, 0, NNODES * sizeof(int), stream);

    gemm2_kernel<<<512, 256, 0, stream>>>(X, A_w, A_b, B_w, B_b, AX, BX16);
    hist_kernel<<<2048, 256, 0, stream>>>(dst, indeg, order);
    scan1_kernel<<<NBLK_P, 256, 0, stream>>>(indeg, lexc, bpart);
    scan2_kernel<<<1, 512, 0, stream>>>(bpart, bscan, rows);
    scan3_kernel<<<NBLK_P, 256, 0, stream>>>(lexc, bscan, rows);
    fill_kernel<<<2048, 256, 0, stream>>>(src, dst, rows, order, esrc);
    agg_kernel<<<NB_STATS, 256, 0, stream>>>(AX, (const unsigned*)BX16, X,
                                             snorm_n, rows, esrc,
                                             out, psum, psq);
    bnstats_kernel<<<1, 1024, 0, stream>>>(psum, psq, gamma, beta, scale, shift);
    final_kernel<<<2048, 256, 0, stream>>>(out, X, scale, shift, out);

    // E_X passthrough LAST: overwrites the scratch region.
    hipMemcpyAsync(out + (size_t)NNODES * D, E_X,
                   (size_t)NEDGES * D * sizeof(float),
                   hipMemcpyDeviceToDevice, stream);
}